// Round 1
// baseline (102.339 us; speedup 1.0000x reference)
//
#include <hip/hip_runtime.h>

// ChannelPolyLayer: out[b,o,x,y] = sum_c coeffs[b,o,c] * prod_v img[b,v,x,y]^powers[c,v]
// B=16, NUM_VARS=3, NUM_OUT=3, H=W=512, NUM_COEFFS=20 (deg<=3 monomials in 3 vars).
//
// Strategy: memory-bound (≈100 MB traffic → ~16 µs floor at 6.3 TB/s).
// Prepass kernel permutes coeffs into a canonical monomial order (derived from
// the `powers` input at runtime — no ordering assumption baked in), so the hot
// kernel evaluates all 20 monomials with straight-line muls (no pow, no
// indexed register arrays) and 60 FMAs with block-uniform (SGPR) coeffs.

#define PLANE (512 * 512)
#define NC 20
#define NV 3
#define NO 3
#define NB 16

// Canonical monomial order for exponent triple (a,b,c), a+b+c<=3:
//  0:1 | 1:x 2:y 3:z | 4:x2 5:xy 6:xz 7:y2 8:yz 9:z2
// 10:x3 11:x2y 12:x2z 13:xy2 14:xyz 15:xz2 16:y3 17:y2z 18:yz2 19:z3
__device__ __forceinline__ int canon_idx(int a, int b, int c) {
    int d = a + b + c;
    if (d == 0) return 0;
    if (d == 1) return a ? 1 : (b ? 2 : 3);
    if (d == 2) {
        if (a == 2) return 4;
        if (a == 1) return (b == 1) ? 5 : 6;
        return (b == 2) ? 7 : ((b == 1) ? 8 : 9);
    }
    // d == 3
    if (a == 3) return 10;
    if (a == 2) return (b == 1) ? 11 : 12;
    if (a == 1) return (b == 2) ? 13 : ((b == 1) ? 14 : 15);
    return (b == 3) ? 16 : ((b == 2) ? 17 : ((b == 1) ? 18 : 19));
}

// Permute coeffs[b,o,c] -> rc[b,o,canon(c)]. 960 entries total; trivial cost.
__global__ void reorder_coeffs_kernel(const float* __restrict__ coeffs,
                                      const float* __restrict__ powers,
                                      float* __restrict__ rc) {
    int i = blockIdx.x * blockDim.x + threadIdx.x;
    if (i >= NB * NO * NC) return;
    int c  = i % NC;
    int bo = i / NC;
    int ea = (int)powers[c * NV + 0];
    int eb = (int)powers[c * NV + 1];
    int ec = (int)powers[c * NV + 2];
    rc[bo * NC + canon_idx(ea, eb, ec)] = coeffs[i];
}

__device__ __forceinline__ void eval_pixel(float x, float y, float z,
                                           const float* __restrict__ c0,
                                           const float* __restrict__ c1,
                                           const float* __restrict__ c2,
                                           float& o0, float& o1, float& o2) {
    float x2 = x * x, y2 = y * y, z2 = z * z;
    float xy = x * y, xz = x * z, yz = y * z;
    float m[NC];
    m[0] = 1.0f;  m[1] = x;      m[2] = y;      m[3] = z;
    m[4] = x2;    m[5] = xy;     m[6] = xz;     m[7] = y2;
    m[8] = yz;    m[9] = z2;     m[10] = x2 * x; m[11] = x2 * y;
    m[12] = x2 * z; m[13] = x * y2; m[14] = xy * z; m[15] = x * z2;
    m[16] = y2 * y; m[17] = y2 * z; m[18] = y * z2; m[19] = z2 * z;
    float a0 = 0.0f, a1 = 0.0f, a2 = 0.0f;
#pragma unroll
    for (int i = 0; i < NC; i++) {
        // c* are block-uniform (base = ws + blockIdx.y*60, literal offsets)
        // -> scalar loads; fmaf(sgpr, vgpr, vgpr) is a single VALU op.
        a0 = fmaf(c0[i], m[i], a0);
        a1 = fmaf(c1[i], m[i], a1);
        a2 = fmaf(c2[i], m[i], a2);
    }
    o0 = a0; o1 = a1; o2 = a2;
}

__global__ __launch_bounds__(256) void channel_poly_kernel(
        const float* __restrict__ img,
        const float* __restrict__ rc,
        float* __restrict__ out) {
    const int b = blockIdx.y;
    const int t = blockIdx.x * blockDim.x + threadIdx.x;  // float4 group id

    const float* base = img + (size_t)b * NV * PLANE;
    const float4 X = ((const float4*)(base))[t];
    const float4 Y = ((const float4*)(base + PLANE))[t];
    const float4 Z = ((const float4*)(base + 2 * PLANE))[t];

    const float* C  = rc + b * NO * NC;
    const float* c0 = C;
    const float* c1 = C + NC;
    const float* c2 = C + 2 * NC;

    float4 O0, O1, O2;
    eval_pixel(X.x, Y.x, Z.x, c0, c1, c2, O0.x, O1.x, O2.x);
    eval_pixel(X.y, Y.y, Z.y, c0, c1, c2, O0.y, O1.y, O2.y);
    eval_pixel(X.z, Y.z, Z.z, c0, c1, c2, O0.z, O1.z, O2.z);
    eval_pixel(X.w, Y.w, Z.w, c0, c1, c2, O0.w, O1.w, O2.w);

    float* obase = out + (size_t)b * NO * PLANE;
    ((float4*)(obase))[t]             = O0;
    ((float4*)(obase + PLANE))[t]     = O1;
    ((float4*)(obase + 2 * PLANE))[t] = O2;
}

extern "C" void kernel_launch(void* const* d_in, const int* in_sizes, int n_in,
                              void* d_out, int out_size, void* d_ws, size_t ws_size,
                              hipStream_t stream) {
    const float* img    = (const float*)d_in[0];
    const float* coeffs = (const float*)d_in[1];
    const float* powers = (const float*)d_in[2];
    float* out = (float*)d_out;
    float* rc  = (float*)d_ws;  // 16*3*20 floats = 3840 B of scratch

    // Prepass: canonicalize coefficient order (runs every call; ws is re-poisoned).
    reorder_coeffs_kernel<<<dim3(4), dim3(256), 0, stream>>>(coeffs, powers, rc);

    // Hot kernel: 4 pixels/thread via float4; grid = (512*512/4/256, 16).
    dim3 grid(PLANE / 4 / 256, NB);
    channel_poly_kernel<<<grid, dim3(256), 0, stream>>>(img, rc, out);
}

// Round 2
// 102.158 us; speedup vs baseline: 1.0018x; 1.0018x over previous
//
#include <hip/hip_runtime.h>

// ChannelPolyLayer: out[b,o,x,y] = sum_c coeffs[b,o,c] * prod_v img[b,v,x,y]^powers[c,v]
// B=16, NUM_VARS=3, NUM_OUT=3, H=W=512, NUM_COEFFS=20 (deg<=3 monomials in 3 vars).
//
// R2: single fused kernel. Each block canonicalizes its batch's 60 coeffs
// through LDS (permutation derived from `powers` at runtime), moves them to
// SGPRs via readfirstlane, then evaluates 4 pixels/thread with straight-line
// monomial muls + 60 scalar-coeff FMAs. Memory-bound: 50 MB read + 50 MB
// write -> ~16 us HBM floor; staging overhead hides under VALU/LDS headroom.

#define PLANE (512 * 512)
#define NC 20
#define NV 3
#define NO 3
#define NB 16

// Canonical monomial order for exponent triple (a,b,c), a+b+c<=3:
//  0:1 | 1:x 2:y 3:z | 4:x2 5:xy 6:xz 7:y2 8:yz 9:z2
// 10:x3 11:x2y 12:x2z 13:xy2 14:xyz 15:xz2 16:y3 17:y2z 18:yz2 19:z3
__device__ __forceinline__ int canon_idx(int a, int b, int c) {
    int d = a + b + c;
    if (d == 0) return 0;
    if (d == 1) return a ? 1 : (b ? 2 : 3);
    if (d == 2) {
        if (a == 2) return 4;
        if (a == 1) return (b == 1) ? 5 : 6;
        return (b == 2) ? 7 : ((b == 1) ? 8 : 9);
    }
    // d == 3
    if (a == 3) return 10;
    if (a == 2) return (b == 1) ? 11 : 12;
    if (a == 1) return (b == 2) ? 13 : ((b == 1) ? 14 : 15);
    return (b == 3) ? 16 : ((b == 2) ? 17 : ((b == 1) ? 18 : 19));
}

__device__ __forceinline__ void eval_pixel(float x, float y, float z,
                                           const float (&cc)[NO * NC],
                                           float& o0, float& o1, float& o2) {
    float x2 = x * x, y2 = y * y, z2 = z * z;
    float xy = x * y, xz = x * z, yz = y * z;
    float m[NC];
    m[0] = 1.0f;    m[1] = x;       m[2] = y;       m[3] = z;
    m[4] = x2;      m[5] = xy;      m[6] = xz;      m[7] = y2;
    m[8] = yz;      m[9] = z2;      m[10] = x2 * x; m[11] = x2 * y;
    m[12] = x2 * z; m[13] = x * y2; m[14] = xy * z; m[15] = x * z2;
    m[16] = y2 * y; m[17] = y2 * z; m[18] = y * z2; m[19] = z2 * z;
    float a0 = 0.0f, a1 = 0.0f, a2 = 0.0f;
#pragma unroll
    for (int i = 0; i < NC; i++) {
        // cc[] values are SGPRs (readfirstlane) -> v_fma_f32 s,v,v single op.
        a0 = fmaf(cc[i],          m[i], a0);
        a1 = fmaf(cc[NC + i],     m[i], a1);
        a2 = fmaf(cc[2 * NC + i], m[i], a2);
    }
    o0 = a0; o1 = a1; o2 = a2;
}

__global__ __launch_bounds__(256) void channel_poly_kernel(
        const float* __restrict__ img,
        const float* __restrict__ coeffs,
        const float* __restrict__ powers,
        float* __restrict__ out) {
    const int b   = blockIdx.y;
    const int tid = threadIdx.x;

    // --- Stage this batch's 60 coeffs into LDS in canonical monomial order ---
    __shared__ float cstage[NO * NC];
    if (tid < NO * NC) {
        int c  = tid % NC;             // coeff index within output channel
        int o  = tid / NC;             // output channel
        int ea = (int)powers[c * NV + 0];
        int eb = (int)powers[c * NV + 1];
        int ec = (int)powers[c * NV + 2];
        cstage[o * NC + canon_idx(ea, eb, ec)] = coeffs[b * NO * NC + tid];
    }
    __syncthreads();

    // Wave-uniform LDS values -> SGPRs so the FMA loop reads scalar operands.
    float cc[NO * NC];
#pragma unroll
    for (int i = 0; i < NO * NC; i++) {
        cc[i] = __int_as_float(__builtin_amdgcn_readfirstlane(__float_as_int(cstage[i])));
    }

    // --- 4 pixels per thread via float4 ---
    const int t = blockIdx.x * blockDim.x + tid;  // float4 group id

    const float* base = img + (size_t)b * NV * PLANE;
    const float4 X = ((const float4*)(base))[t];
    const float4 Y = ((const float4*)(base + PLANE))[t];
    const float4 Z = ((const float4*)(base + 2 * PLANE))[t];

    float4 O0, O1, O2;
    eval_pixel(X.x, Y.x, Z.x, cc, O0.x, O1.x, O2.x);
    eval_pixel(X.y, Y.y, Z.y, cc, O0.y, O1.y, O2.y);
    eval_pixel(X.z, Y.z, Z.z, cc, O0.z, O1.z, O2.z);
    eval_pixel(X.w, Y.w, Z.w, cc, O0.w, O1.w, O2.w);

    float* obase = out + (size_t)b * NO * PLANE;
    ((float4*)(obase))[t]             = O0;
    ((float4*)(obase + PLANE))[t]     = O1;
    ((float4*)(obase + 2 * PLANE))[t] = O2;
}

extern "C" void kernel_launch(void* const* d_in, const int* in_sizes, int n_in,
                              void* d_out, int out_size, void* d_ws, size_t ws_size,
                              hipStream_t stream) {
    const float* img    = (const float*)d_in[0];
    const float* coeffs = (const float*)d_in[1];
    const float* powers = (const float*)d_in[2];
    float* out = (float*)d_out;
    (void)d_ws; (void)ws_size;

    // Single fused kernel: 4 pixels/thread; grid = (512*512/4/256, 16).
    dim3 grid(PLANE / 4 / 256, NB);
    channel_poly_kernel<<<grid, dim3(256), 0, stream>>>(img, coeffs, powers, out);
}